// Round 2
// baseline (808.301 us; speedup 1.0000x reference)
//
#include <hip/hip_runtime.h>
#include <hip/hip_bf16.h>

// Fused 8-layer tanh RNN (B=4096, T=512, H=24, in=6) + final 24->3 FC.
//
// Layer-pipelined persistent-weight kernel, TPP=2 timesteps per barrier:
//  - Block = 512 threads = 8 waves; wave l permanently owns layer l.
//  - Block processes NBB=4 batch elements for all T. Layers are skewed by
//    TPP=2 timesteps: at phase p, wave l computes t = 2*(p-l) and 2*(p-l)+1.
//    One __syncthreads per phase (263 total vs 519 at 1 t/step).
//  - Lane = (b: batch 0..3) x (jl: j-trio 0..7) x (ks: k-half 0..1) of the
//    48-long concat [input(24, zero-padded for layer 0) | h(24)].
//  - Each lane's 3x24 weight slab lives in VGPRs for the whole kernel:
//    zero per-step weight traffic. 72 FMAs/lane/t = 100% useful MACs.
//  - k-half partials combined with one shfl_xor(1) butterfly (DPP).
//  - Activations flow through LDS: ibuf[l][phase parity][slot][b][24]
//    (from layer l-1, double-buffered), hbuf[l][b][24] (own h state).
//    Intra-phase h reuse needs only s_waitcnt lgkmcnt(0) (same wave).
//  - +16B pad between ibuf and hbuf: ks=0/ks=1 halves of the fused
//    ds_read_b128 land in disjoint bank groups (conflict-free).
//  - Wave 0 prefetches x(phase+1) one phase ahead (50 MB total, L3-hot).

#define T_LEN  512
#define HD     24
#define NL     8
#define NBB    4
#define TPP    2
#define NPHASE (T_LEN / TPP + NL - 1)   // 263

struct SMem {
    float ibuf[NL][2][TPP][NBB][HD];  // 12288 B, bank-aligned per row (96 B)
    float pad[4];                     // shift hbuf by 4 banks vs ibuf
    float hbuf[NL][NBB][HD];          // 3072 B
};

__device__ __forceinline__ float tanh_acc(float v) {
    // tanh(v) = 1 - 2/(exp(2v)+1); rcp refined by one Newton step (~1 ulp).
    float e = __expf(v + v);
    float d = e + 1.0f;
    float r = __builtin_amdgcn_rcpf(d);
    r = r * fmaf(-d, r, 2.0f);
    return fmaf(-2.0f, r, 1.0f);
}

__global__ __launch_bounds__(512, 4) void rnn_fused_pipeline(
    const float* __restrict__ x,     // (4096, 512, 6)
    const float* __restrict__ Wih0,  // (24, 6)
    const float* __restrict__ WihR,  // (7, 24, 24)
    const float* __restrict__ Whh,   // (8, 24, 24)
    const float* __restrict__ bih,   // (8, 24)
    const float* __restrict__ bhh,   // (8, 24)
    const float* __restrict__ fcw,   // (3, 24)
    const float* __restrict__ fcb,   // (3,)
    float* __restrict__ out)         // (4096, 3)
{
    __shared__ SMem sm;

    const int tid  = threadIdx.x;
    const int l    = __builtin_amdgcn_readfirstlane(tid >> 6); // wave-uniform SGPR
    const int lane = tid & 63;
    const int b    = lane >> 4;
    const int jl   = (lane >> 1) & 7;
    const int ks   = lane & 1;
    const int j0   = jl * 3;

    // ---- zero-init LDS (h(-1)=0; x pad lanes [6..23] stay 0 forever) ----
    {
        float* smf = (float*)&sm;
        for (int i = tid; i < (int)(sizeof(SMem) / 4); i += 512) smf[i] = 0.0f;
    }

    // ---- persistent per-lane weights (one-time; L2/L3-hot across blocks) ----
    float w[3][HD];
    float bias[3];
    #pragma unroll
    for (int s = 0; s < 3; ++s) {
        const int j = j0 + s;
        bias[s] = (ks == 0) ? (bih[l * HD + j] + bhh[l * HD + j]) : 0.0f;
        #pragma unroll
        for (int kk = 0; kk < HD; ++kk) {
            float wv;
            if (ks == 0) {
                if (l == 0) wv = (kk < 6) ? Wih0[j * 6 + kk] : 0.0f;
                else        wv = WihR[((l - 1) * HD + j) * HD + kk];
            } else {
                wv = Whh[(l * HD + j) * HD + kk];
            }
            w[s][kk] = wv;
        }
    }

    const long bbase = (long)blockIdx.x * NBB;

    __syncthreads();  // zeros visible before x preload overwrites ibuf[0][1]

    // ---- preload x(t=0,1) into ibuf[0][parity=1][slot] (read at phase 0) ----
    if (tid < NBB * 6 * TPP) {
        const int bb = tid / (6 * TPP);
        const int sl = (tid / 6) % TPP;
        const int ii = tid % 6;
        sm.ibuf[0][1][sl][bb][ii] = x[((bbase + bb) * T_LEN + sl) * 6 + ii];
    }
    __syncthreads();

    // per-lane LDS read bases
    const float* rd_h     = &sm.hbuf[l][b][0];
    const float* rd_ibase = &sm.ibuf[l][0][0][b][0];
    // [l][par][sl][b][0] = rd_ibase + par*(TPP*NBB*HD) + sl*(NBB*HD)

    for (int ph = 0; ph < NPHASE; ++ph) {
        const int  pl     = ph - l;                        // uniform
        const bool active = (pl >= 0) && (pl < T_LEN / TPP);
        const int  rpar   = (ph + 1) & 1;                  // read parity
        const int  wpar   = ph & 1;                        // write parity

        // ---- wave 0: prefetch x for phase ph+1 into registers ----
        float xv  = 0.0f;
        bool  xok = false;
        if (l == 0 && lane < NBB * 6 * TPP) {
            const int bb = lane / (6 * TPP);
            const int sl = (lane / 6) % TPP;
            const int ii = lane % 6;
            const int t  = TPP * (ph + 1) + sl;
            if (t < T_LEN) {
                xv  = x[((bbase + bb) * T_LEN + t) * 6 + ii];
                xok = true;
            }
        }

        if (active) {
            const float* ri0  = rd_ibase + rpar * (TPP * NBB * HD);
            const float* srcA = ks ? rd_h : ri0;                 // slot 0
            const float* srcB = ks ? rd_h : (ri0 + NBB * HD);    // slot 1

            #pragma unroll
            for (int sl = 0; sl < TPP; ++sl) {
                const float4* src4 =
                    reinterpret_cast<const float4*>(sl ? srcB : srcA);

                float acc0 = bias[0], acc1 = bias[1], acc2 = bias[2];
                #pragma unroll
                for (int c = 0; c < 6; ++c) {        // 6x ds_read_b128
                    const float4 v4 = src4[c];
                    const float av[4] = {v4.x, v4.y, v4.z, v4.w};
                    #pragma unroll
                    for (int q = 0; q < 4; ++q) {    // 72 FMAs, 3 indep chains
                        acc0 = fmaf(w[0][c * 4 + q], av[q], acc0);
                        acc1 = fmaf(w[1][c * 4 + q], av[q], acc1);
                        acc2 = fmaf(w[2][c * 4 + q], av[q], acc2);
                    }
                }
                // combine k-halves (both lanes of the pair get the total)
                acc0 += __shfl_xor(acc0, 1, 64);
                acc1 += __shfl_xor(acc1, 1, 64);
                acc2 += __shfl_xor(acc2, 1, 64);

                const float h0 = tanh_acc(acc0);
                const float h1 = tanh_acc(acc1);
                const float h2 = tanh_acc(acc2);

                if (ks == 0) {
                    // own recurrent state for t+1
                    sm.hbuf[l][b][j0 + 0] = h0;
                    sm.hbuf[l][b][j0 + 1] = h1;
                    sm.hbuf[l][b][j0 + 2] = h2;
                } else if (l < NL - 1) {
                    // feed layer l+1 (runs one phase behind)
                    sm.ibuf[l + 1][wpar][sl][b][j0 + 0] = h0;
                    sm.ibuf[l + 1][wpar][sl][b][j0 + 1] = h1;
                    sm.ibuf[l + 1][wpar][sl][b][j0 + 2] = h2;
                }

                if (sl + 1 < TPP) {
                    // same-wave LDS producer->consumer: drain DS queue and
                    // forbid compiler reordering of the slot-1 reads upward.
                    asm volatile("s_waitcnt lgkmcnt(0)" ::: "memory");
                }
            }
        }

        // ---- wave 0: commit prefetched x into ibuf[0][wpar] ----
        if (xok) {
            const int bb = lane / (6 * TPP);
            const int sl = (lane / 6) % TPP;
            const int ii = lane % 6;
            sm.ibuf[0][wpar][sl][bb][ii] = xv;
        }

        __syncthreads();  // one barrier per phase (2 timesteps)
    }

    // ---- FC epilogue: out[b] = fc_w @ h7(T-1) + fc_b ----
    if (tid < NBB * 3) {
        const int bb = tid / 3, k = tid % 3;
        float acc = fcb[k];
        #pragma unroll
        for (int j = 0; j < HD; ++j)
            acc = fmaf(fcw[k * HD + j], sm.hbuf[NL - 1][bb][j], acc);
        out[(bbase + bb) * 3 + k] = acc;
    }
}

extern "C" void kernel_launch(void* const* d_in, const int* in_sizes, int n_in,
                              void* d_out, int out_size, void* d_ws, size_t ws_size,
                              hipStream_t stream) {
    const float* x    = (const float*)d_in[0];
    const float* Wih0 = (const float*)d_in[1];
    const float* WihR = (const float*)d_in[2];
    const float* Whh  = (const float*)d_in[3];
    const float* bih  = (const float*)d_in[4];
    const float* bhh  = (const float*)d_in[5];
    const float* fcw  = (const float*)d_in[6];
    const float* fcb  = (const float*)d_in[7];
    float* out = (float*)d_out;

    dim3 grid(4096 / NBB);   // 1024 blocks
    dim3 block(512);         // 8 waves: one per layer
    hipLaunchKernelGGL(rnn_fused_pipeline, grid, block, 0, stream,
                       x, Wih0, WihR, Whh, bih, bhh, fcw, fcb, out);
}

// Round 4
// 805.559 us; speedup vs baseline: 1.0034x; 1.0034x over previous
//
#include <hip/hip_runtime.h>
#include <hip/hip_bf16.h>

// Fused 8-layer tanh RNN (B=4096, T=512, H=24, in=6) + final 24->3 FC.
//
// Layer-pipelined persistent-weight kernel, TPP=2 timesteps per barrier.
// (See round-1 comments for the full design.)
//
// ROUND-2/3 CHANGE (single variable): __attribute__((amdgpu_waves_per_eu(4,4))).
// Round-1 data showed VGPR_Count=56 with VALUBusy=94.5% -- the allocator
// targeted 8 waves/EU and demoted the 72 persistent weights to AGPRs, so the
// hot loop pays a v_accvgpr_read before every FMA (~2x VALU instructions).
// Pinning waves/EU to exactly 4 gives a 128-VGPR budget; the ~112-reg live
// set (72 w + 24 a + accs + ptrs) then stays in VGPRs.

#define T_LEN  512
#define HD     24
#define NL     8
#define NBB    4
#define TPP    2
#define NPHASE (T_LEN / TPP + NL - 1)   // 263

struct SMem {
    float ibuf[NL][2][TPP][NBB][HD];  // 12288 B
    float pad[4];
    float hbuf[NL][NBB][HD];          // 3072 B
};

__device__ __forceinline__ float tanh_acc(float v) {
    // tanh(v) = 1 - 2/(exp(2v)+1); rcp refined by one Newton step (~1 ulp).
    float e = __expf(v + v);
    float d = e + 1.0f;
    float r = __builtin_amdgcn_rcpf(d);
    r = r * fmaf(-d, r, 2.0f);
    return fmaf(-2.0f, r, 1.0f);
}

__global__ __launch_bounds__(512)
__attribute__((amdgpu_waves_per_eu(4, 4)))
void rnn_fused_pipeline(
    const float* __restrict__ x,     // (4096, 512, 6)
    const float* __restrict__ Wih0,  // (24, 6)
    const float* __restrict__ WihR,  // (7, 24, 24)
    const float* __restrict__ Whh,   // (8, 24, 24)
    const float* __restrict__ bih,   // (8, 24)
    const float* __restrict__ bhh,   // (8, 24)
    const float* __restrict__ fcw,   // (3, 24)
    const float* __restrict__ fcb,   // (3,)
    float* __restrict__ out)         // (4096, 3)
{
    __shared__ SMem sm;

    const int tid  = threadIdx.x;
    const int l    = __builtin_amdgcn_readfirstlane(tid >> 6); // wave-uniform SGPR
    const int lane = tid & 63;
    const int b    = lane >> 4;
    const int jl   = (lane >> 1) & 7;
    const int ks   = lane & 1;
    const int j0   = jl * 3;

    // ---- zero-init LDS (h(-1)=0; x pad lanes [6..23] stay 0 forever) ----
    {
        float* smf = (float*)&sm;
        for (int i = tid; i < (int)(sizeof(SMem) / 4); i += 512) smf[i] = 0.0f;
    }

    // ---- persistent per-lane weights (one-time; L2/L3-hot across blocks) ----
    float w[3][HD];
    float bias[3];
    #pragma unroll
    for (int s = 0; s < 3; ++s) {
        const int j = j0 + s;
        bias[s] = (ks == 0) ? (bih[l * HD + j] + bhh[l * HD + j]) : 0.0f;
        #pragma unroll
        for (int kk = 0; kk < HD; ++kk) {
            float wv;
            if (ks == 0) {
                if (l == 0) wv = (kk < 6) ? Wih0[j * 6 + kk] : 0.0f;
                else        wv = WihR[((l - 1) * HD + j) * HD + kk];
            } else {
                wv = Whh[(l * HD + j) * HD + kk];
            }
            w[s][kk] = wv;
        }
    }

    const long bbase = (long)blockIdx.x * NBB;

    __syncthreads();  // zeros visible before x preload overwrites ibuf[0][1]

    // ---- preload x(t=0,1) into ibuf[0][parity=1][slot] (read at phase 0) ----
    if (tid < NBB * 6 * TPP) {
        const int bb = tid / (6 * TPP);
        const int sl = (tid / 6) % TPP;
        const int ii = tid % 6;
        sm.ibuf[0][1][sl][bb][ii] = x[((bbase + bb) * T_LEN + sl) * 6 + ii];
    }
    __syncthreads();

    // per-lane LDS read bases
    const float* rd_h     = &sm.hbuf[l][b][0];
    const float* rd_ibase = &sm.ibuf[l][0][0][b][0];
    // [l][par][sl][b][0] = rd_ibase + par*(TPP*NBB*HD) + sl*(NBB*HD)

    for (int ph = 0; ph < NPHASE; ++ph) {
        const int  pl     = ph - l;                        // uniform
        const bool active = (pl >= 0) && (pl < T_LEN / TPP);
        const int  rpar   = (ph + 1) & 1;                  // read parity
        const int  wpar   = ph & 1;                        // write parity

        // ---- wave 0: prefetch x for phase ph+1 into registers ----
        float xv  = 0.0f;
        bool  xok = false;
        if (l == 0 && lane < NBB * 6 * TPP) {
            const int bb = lane / (6 * TPP);
            const int sl = (lane / 6) % TPP;
            const int ii = lane % 6;
            const int t  = TPP * (ph + 1) + sl;
            if (t < T_LEN) {
                xv  = x[((bbase + bb) * T_LEN + t) * 6 + ii];
                xok = true;
            }
        }

        if (active) {
            const float* ri0  = rd_ibase + rpar * (TPP * NBB * HD);
            const float* srcA = ks ? rd_h : ri0;                 // slot 0
            const float* srcB = ks ? rd_h : (ri0 + NBB * HD);    // slot 1

            #pragma unroll
            for (int sl = 0; sl < TPP; ++sl) {
                const float4* src4 =
                    reinterpret_cast<const float4*>(sl ? srcB : srcA);

                float acc0 = bias[0], acc1 = bias[1], acc2 = bias[2];
                #pragma unroll
                for (int c = 0; c < 6; ++c) {        // 6x ds_read_b128
                    const float4 v4 = src4[c];
                    const float av[4] = {v4.x, v4.y, v4.z, v4.w};
                    #pragma unroll
                    for (int q = 0; q < 4; ++q) {    // 72 FMAs, 3 indep chains
                        acc0 = fmaf(w[0][c * 4 + q], av[q], acc0);
                        acc1 = fmaf(w[1][c * 4 + q], av[q], acc1);
                        acc2 = fmaf(w[2][c * 4 + q], av[q], acc2);
                    }
                }
                // combine k-halves (both lanes of the pair get the total)
                acc0 += __shfl_xor(acc0, 1, 64);
                acc1 += __shfl_xor(acc1, 1, 64);
                acc2 += __shfl_xor(acc2, 1, 64);

                const float h0 = tanh_acc(acc0);
                const float h1 = tanh_acc(acc1);
                const float h2 = tanh_acc(acc2);

                if (ks == 0) {
                    // own recurrent state for t+1
                    sm.hbuf[l][b][j0 + 0] = h0;
                    sm.hbuf[l][b][j0 + 1] = h1;
                    sm.hbuf[l][b][j0 + 2] = h2;
                } else if (l < NL - 1) {
                    // feed layer l+1 (runs one phase behind)
                    sm.ibuf[l + 1][wpar][sl][b][j0 + 0] = h0;
                    sm.ibuf[l + 1][wpar][sl][b][j0 + 1] = h1;
                    sm.ibuf[l + 1][wpar][sl][b][j0 + 2] = h2;
                }

                if (sl + 1 < TPP) {
                    // same-wave LDS producer->consumer: drain DS queue and
                    // forbid compiler reordering of the slot-1 reads upward.
                    asm volatile("s_waitcnt lgkmcnt(0)" ::: "memory");
                }
            }
        }

        // ---- wave 0: commit prefetched x into ibuf[0][wpar] ----
        if (xok) {
            const int bb = lane / (6 * TPP);
            const int sl = (lane / 6) % TPP;
            const int ii = lane % 6;
            sm.ibuf[0][wpar][sl][bb][ii] = xv;
        }

        __syncthreads();  // one barrier per phase (2 timesteps)
    }

    // ---- FC epilogue: out[b] = fc_w @ h7(T-1) + fc_b ----
    if (tid < NBB * 3) {
        const int bb = tid / 3, k = tid % 3;
        float acc = fcb[k];
        #pragma unroll
        for (int j = 0; j < HD; ++j)
            acc = fmaf(fcw[k * HD + j], sm.hbuf[NL - 1][bb][j], acc);
        out[(bbase + bb) * 3 + k] = acc;
    }
}

extern "C" void kernel_launch(void* const* d_in, const int* in_sizes, int n_in,
                              void* d_out, int out_size, void* d_ws, size_t ws_size,
                              hipStream_t stream) {
    const float* x    = (const float*)d_in[0];
    const float* Wih0 = (const float*)d_in[1];
    const float* WihR = (const float*)d_in[2];
    const float* Whh  = (const float*)d_in[3];
    const float* bih  = (const float*)d_in[4];
    const float* bhh  = (const float*)d_in[5];
    const float* fcw  = (const float*)d_in[6];
    const float* fcb  = (const float*)d_in[7];
    float* out = (float*)d_out;

    dim3 grid(4096 / NBB);   // 1024 blocks
    dim3 block(512);         // 8 waves: one per layer
    hipLaunchKernelGGL(rnn_fused_pipeline, grid, block, 0, stream,
                       x, Wih0, WihR, Whh, bih, bhh, fcw, fcb, out);
}

// Round 5
// 796.581 us; speedup vs baseline: 1.0147x; 1.0113x over previous
//
#include <hip/hip_runtime.h>
#include <hip/hip_bf16.h>

// Fused 8-layer tanh RNN (B=4096, T=512, H=24, in=6) + final 24->3 FC.
//
// Layer-pipelined persistent-weight kernel, TPP=2 timesteps per barrier.
// ROUND-4 REDESIGN: live-set now sized to the 56-64 arch VGPRs the
// allocator actually grants (rounds 1-3 proved it refuses more and the
// 72-weight slab bounced through AGPR copies -> ~4x VALU bloat).
//   lane = (b: 0..1) x (jl: 0..7) x (ks: 0..3)   [ks inside a quad]
//   per-lane weights: 3 j x 12 k = 36 floats (+1 bias) -- fits arch VGPRs.
//   reduction: 2-level quad_perm DPP butterfly (guaranteed VALU, no LDS).
//   tanh distributed across quad: lane ks=r finalizes output j0+r (1 tanh).
//   NBB=2 batch/block -> 2048 blocks, ~8.3KB LDS, 4 blocks/CU, 32 waves/CU.

#define T_LEN  512
#define HD     24
#define NL     8
#define NBB    2
#define TPP    2
#define NPHASE (T_LEN / TPP + NL - 1)   // 263

struct SMem {
    // strides (floats): j:1, b:24, sl:48, par:96, l:192
    float ibuf[NL][2][TPP][NBB][HD];  // 1536 floats
    float pad[16];                    // bank-class offset for hbuf
    float hbuf[NL][NBB * HD + 16];    // per-layer 256B stride; [l][b*24+j]
};

__device__ __forceinline__ float tanh_acc(float v) {
    // tanh(v) = 1 - 2/(exp(2v)+1); rcp refined by one Newton step (~1 ulp).
    float e = __expf(v + v);
    float d = e + 1.0f;
    float r = __builtin_amdgcn_rcpf(d);
    r = r * fmaf(-d, r, 2.0f);
    return fmaf(-2.0f, r, 1.0f);
}

// butterfly add across quad lanes: CTRL=0xB1 -> xor1, CTRL=0x4E -> xor2
template <int CTRL>
__device__ __forceinline__ float quad_bfly_add(float v) {
    int i = __builtin_bit_cast(int, v);
    int s = __builtin_amdgcn_update_dpp(i, i, CTRL, 0xF, 0xF, false);
    return v + __builtin_bit_cast(float, s);
}

__global__ __launch_bounds__(512) void rnn_fused_pipeline(
    const float* __restrict__ x,     // (4096, 512, 6)
    const float* __restrict__ Wih0,  // (24, 6)
    const float* __restrict__ WihR,  // (7, 24, 24)
    const float* __restrict__ Whh,   // (8, 24, 24)
    const float* __restrict__ bih,   // (8, 24)
    const float* __restrict__ bhh,   // (8, 24)
    const float* __restrict__ fcw,   // (3, 24)
    const float* __restrict__ fcb,   // (3,)
    float* __restrict__ out)         // (4096, 3)
{
    __shared__ __align__(128) SMem sm;

    const int tid  = threadIdx.x;
    const int l    = __builtin_amdgcn_readfirstlane(tid >> 6); // wave == layer
    const int lane = tid & 63;
    const int b    = lane >> 5;        // batch within block (0..1)
    const int jl   = (lane >> 2) & 7;  // j-trio
    const int ks   = lane & 3;         // k-quarter of concat [in(24)|h(24)]
    const int j0   = jl * 3;
    const int ks01 = ks & 1;           // which 12-chunk within the half
    const int kh   = ks >> 1;          // 0: input half (Wih), 1: h half (Whh)

    // ---- zero-init LDS (h(-1)=0; x pad cols [6..23] stay 0 forever) ----
    {
        float* smf = (float*)&sm;
        for (int i = tid; i < (int)(sizeof(SMem) / 4); i += 512) smf[i] = 0.0f;
    }

    // ---- per-lane persistent weights: 3 j-rows x 12 k-cols ----
    float w[3][12];
    #pragma unroll
    for (int s = 0; s < 3; ++s) {
        const int j = j0 + s;
        #pragma unroll
        for (int kk = 0; kk < 12; ++kk) {
            const int col = ks01 * 12 + kk;
            float wv;
            if (kh == 0) {
                if (l == 0) wv = (col < 6) ? Wih0[j * 6 + col] : 0.0f;
                else        wv = WihR[((l - 1) * HD + j) * HD + col];
            } else {
                wv = Whh[(l * HD + j) * HD + col];
            }
            w[s][kk] = wv;
        }
    }
    // this lane finalizes output j0+ks (ks<3); bias folded post-reduction
    const int  bj    = j0 + ((ks == 3) ? 0 : ks);
    const float blane = bih[l * HD + bj] + bhh[l * HD + bj];

    const long bbase = (long)blockIdx.x * NBB;

    // ---- x prefetch lane mapping (wave 0, 24 lanes: 2b x 2sl x 6i) ----
    const bool isx = (l == 0) && (lane < NBB * 6 * TPP);
    const int  xbb = lane / 12, xrem = lane % 12;
    const int  xsl = xrem / 6,  xii  = xrem % 6;
    const float* xp = x + ((bbase + xbb) * T_LEN + xsl) * 6 + xii;

    __syncthreads();  // zeros visible before x preload writes ibuf[0][1]

    if (isx) sm.ibuf[0][1][xsl][xbb][xii] = xp[0];   // t = xsl (0,1)
    __syncthreads();

    // ---- per-lane LDS pointers ----
    float* const ib   = &sm.ibuf[0][0][0][0][0];
    const float* base0 = ib + l * 192 + b * HD + ks01 * 12;        // kh==0
    const float* baseH = &sm.hbuf[l][b * HD + ks01 * 12];          // kh==1
    const float* rd_p0 = kh ? baseH : base0;        // read base at parity 0
    const float* rd_p1 = kh ? baseH : base0 + 96;   // read base at parity 1
    const int    sloff = kh ? 0 : 48;               // slot-1 offset

    float*       hw = &sm.hbuf[l][b * HD + j0 + ks];               // ks<3 only
    float* const iw = ib + (l + 1) * 192 + b * HD + j0 + ks;       // + wpar*96 + sl*48

    for (int ph = 0; ph < NPHASE; ++ph) {
        const int  pl     = ph - l;                         // uniform
        const bool active = (pl >= 0) && (pl < T_LEN / TPP);
        const int  rpar   = (ph + 1) & 1;
        const int  wpar   = ph & 1;
        const bool xgo    = isx && (ph < T_LEN / TPP - 1);

        // ---- wave 0: prefetch x for phase ph+1 (t = 2(ph+1)+xsl) ----
        float xv = 0.0f;
        if (xgo) xv = xp[12 * (ph + 1)];

        if (active) {
            const float* r0 = rpar ? rd_p1 : rd_p0;

            #pragma unroll
            for (int sl = 0; sl < TPP; ++sl) {
                const float4* src4 =
                    reinterpret_cast<const float4*>(sl ? (r0 + sloff) : r0);

                float acc0 = 0.0f, acc1 = 0.0f, acc2 = 0.0f;
                #pragma unroll
                for (int c = 0; c < 3; ++c) {        // 3x ds_read_b128
                    const float4 v4 = src4[c];
                    const float av[4] = {v4.x, v4.y, v4.z, v4.w};
                    #pragma unroll
                    for (int q = 0; q < 4; ++q) {    // 36 FMAs, 3 indep chains
                        acc0 = fmaf(w[0][c * 4 + q], av[q], acc0);
                        acc1 = fmaf(w[1][c * 4 + q], av[q], acc1);
                        acc2 = fmaf(w[2][c * 4 + q], av[q], acc2);
                    }
                }
                // quad butterfly: all 4 ks-lanes get the full 48-k sums
                acc0 = quad_bfly_add<0xB1>(acc0);
                acc0 = quad_bfly_add<0x4E>(acc0);
                acc1 = quad_bfly_add<0xB1>(acc1);
                acc1 = quad_bfly_add<0x4E>(acc1);
                acc2 = quad_bfly_add<0xB1>(acc2);
                acc2 = quad_bfly_add<0x4E>(acc2);

                // distributed tanh: lane ks=r finalizes output j0+r
                const float pre = (ks == 0) ? acc0 : (ks == 1) ? acc1 : acc2;
                const float h   = tanh_acc(pre + blane);

                if (ks < 3) {
                    *hw = h;                                   // own h state
                    if (l < NL - 1)
                        iw[wpar * 96 + sl * 48] = h;           // feed layer l+1
                }

                if (sl + 1 < TPP) {
                    // same-wave LDS RAW (h(t) -> h(t+1)): drain DS queue,
                    // forbid reordering of slot-1 reads upward.
                    asm volatile("s_waitcnt lgkmcnt(0)" ::: "memory");
                }
            }
        }

        // ---- wave 0: commit prefetched x into ibuf[0][wpar] ----
        if (xgo) sm.ibuf[0][wpar][xsl][xbb][xii] = xv;

        __syncthreads();  // one barrier per phase (2 timesteps)
    }

    // ---- FC epilogue: out[b] = fc_w @ h7(T-1) + fc_b ----
    if (tid < NBB * 3) {
        const int bb = tid / 3, k = tid % 3;
        float acc = fcb[k];
        #pragma unroll
        for (int j = 0; j < HD; ++j)
            acc = fmaf(fcw[k * HD + j], sm.hbuf[NL - 1][bb * HD + j], acc);
        out[(bbase + bb) * 3 + k] = acc;
    }
}

extern "C" void kernel_launch(void* const* d_in, const int* in_sizes, int n_in,
                              void* d_out, int out_size, void* d_ws, size_t ws_size,
                              hipStream_t stream) {
    const float* x    = (const float*)d_in[0];
    const float* Wih0 = (const float*)d_in[1];
    const float* WihR = (const float*)d_in[2];
    const float* Whh  = (const float*)d_in[3];
    const float* bih  = (const float*)d_in[4];
    const float* bhh  = (const float*)d_in[5];
    const float* fcw  = (const float*)d_in[6];
    const float* fcb  = (const float*)d_in[7];
    float* out = (float*)d_out;

    dim3 grid(4096 / NBB);   // 2048 blocks
    dim3 block(512);         // 8 waves: one per layer
    hipLaunchKernelGGL(rnn_fused_pipeline, grid, block, 0, stream,
                       x, Wih0, WihR, Whh, bih, bhh, fcw, fcb, out);
}